// Round 6
// baseline (2130.058 us; speedup 1.0000x reference)
//
#include <hip/hip_runtime.h>

#define DEV __device__ __forceinline__

typedef unsigned short u16;
using bf16x8 = __attribute__((ext_vector_type(8))) __bf16;
using f32x4  = __attribute__((ext_vector_type(4))) float;

DEV u16 f2bf(float f){
  unsigned u = __float_as_uint(f);
  u += 0x7fffu + ((u >> 16) & 1u);   // round-to-nearest-even
  return (u16)(u >> 16);
}
DEV float sigf(float x){ return 1.f / (1.f + __expf(-x)); }
DEV float tanh_(float x){ return 2.f / (1.f + __expf(-2.f*x)) - 1.f; } // safe at +/-inf

DEV void async16(const u16* g, u16* l){
  __builtin_amdgcn_global_load_lds(
      (const __attribute__((address_space(1))) unsigned int*)g,
      (__attribute__((address_space(3))) unsigned int*)l, 16, 0, 0);
}

// ---------------- BatchNorm (training-mode batch stats, biased var) ----------
__global__ void bn_stats(const float* __restrict__ z, float* __restrict__ ps, float* __restrict__ pq){
  int bx = blockIdx.x; int rg = bx >> 2, cg = bx & 3;
  int c = cg*256 + threadIdx.x;
  float s = 0.f, q = 0.f;
  for (int r = rg*64; r < rg*64 + 64; ++r){ float v = z[r*1024 + c]; s += v; q += v*v; }
  ps[rg*1024 + c] = s; pq[rg*1024 + c] = q;
}

__global__ void bn_fin(const float* __restrict__ ps, const float* __restrict__ pq,
                       const float* __restrict__ gam, const float* __restrict__ bet,
                       float* __restrict__ sc, float* __restrict__ sh){
  int c = blockIdx.x*256 + threadIdx.x;
  float s = 0.f, q = 0.f;
  for (int rg = 0; rg < 16; ++rg){ s += ps[rg*1024 + c]; q += pq[rg*1024 + c]; }
  float mean = s * (1.f/1024.f);
  float var  = q * (1.f/1024.f) - mean*mean;
  float k = gam[c] * rsqrtf(var + 1e-5f);
  sc[c] = k; sh[c] = bet[c] - mean*k;
}

// zn -> h0 (bf16), h1 (bf16), c0 (f32), c1 (f32)
__global__ void bn_norm(const float* __restrict__ z, const float* __restrict__ sc, const float* __restrict__ sh,
                        u16* __restrict__ h0, u16* __restrict__ h1,
                        float* __restrict__ c0, float* __restrict__ c1){
  int bx = blockIdx.x; int rg = bx >> 2, cg = bx & 3;
  int c = cg*256 + threadIdx.x;
  float k = sc[c], b = sh[c];
  for (int r = rg*64; r < rg*64 + 64; ++r){
    float v = z[r*1024 + c]*k + b;
    u16 hv = f2bf(v);
    h0[r*1024 + c] = hv; h1[r*1024 + c] = hv;
    c0[r*1024 + c] = v;  c1[r*1024 + c] = v;
  }
}

// ---------------- weight pack: MFMA-fragment order (+gate permutation) -------
// Chunk c = (((bx*nkt + kt)*2 + ksub)*8 + j): 1KB = 64 lanes x 16B.
// Lane l: B[n = bx*128 + j*16 + (l&15)][k = kt*64 + ksub*32 + (l>>4)*8 ..+8].
// permute: packed N-index -> source row (gate-interleave), sources ld=1024.
__global__ void pack_w(const float* __restrict__ src0, const float* __restrict__ src1,
                       int KloA, int K, int permute, u16* __restrict__ dst){
  int c = blockIdx.x*4 + (threadIdx.x >> 6);
  int lane = threadIdx.x & 63;
  int j = c & 7, ksub = (c>>3)&1;
  int rest = c >> 4;
  int nkt = K >> 6;
  int kt = rest % nkt, bx = rest / nkt;
  int rn = bx*128 + j*16 + (lane & 15);
  int row = rn;
  if (permute){ int gate=(rn>>4)&3; int u=(rn&15)|((rn>>6)<<4); row=(gate<<10)+u; }
  int k0 = kt*64 + ksub*32 + (lane>>4)*8;
  const float* sp; int kk;
  if (k0 < KloA){ sp = src0; kk = k0; } else { sp = src1; kk = k0 - KloA; }
  const float4* v = (const float4*)(sp + (size_t)row*1024 + kk);
  float4 a = v[0], b = v[1];
  ushort4 o0; o0.x=f2bf(a.x); o0.y=f2bf(a.y); o0.z=f2bf(a.z); o0.w=f2bf(a.w);
  ushort4 o1; o1.x=f2bf(b.x); o1.y=f2bf(b.y); o1.z=f2bf(b.z); o1.w=f2bf(b.w);
  ushort4* d = (ushort4*)(dst + ((size_t)c<<9) + lane*8);
  d[0]=o0; d[1]=o1;
}

__global__ void bias_k(const float* __restrict__ bi0, const float* __restrict__ bh0,
                       const float* __restrict__ bi1, const float* __restrict__ bh1,
                       float* __restrict__ bx0, float* __restrict__ b1){
  int c = blockIdx.x*256 + threadIdx.x;           // 0..4095
  int gate = (c>>4)&3; int u = (c&15) | ((c>>6)<<4); int r = (gate<<10) + u;
  bx0[c] = bi0[r] + bh0[r];
  b1[c]  = bi1[r] + bh1[r];
}

// ---------------- GEMM core: C(256x128) = A(M,K) @ B(N,K)^T, bf16 MFMA ------
// 512 threads, 8 waves ALL along M (wave tile 32x128) -> zero A-read
// duplication; 32 MFMA/wave per barrier.
// A: global_load_lds -> LDS, BK=64, NBUF=2 (2 x 32KB), single barrier/iter,
//    16B-slot XOR swizzle (slot ^= row&7) via pre-swizzled global source.
// B: fragment-packed global, DIRECT global->VGPR (bP/bQ ksub double-buffer).
// vmcnt FIFO per iter: bQ(8), stageA(kt+1)(4), [ksub0 MFMA], bP'(8),
// [ksub1: compiler waits bQ => <=12], manual vmcnt(8) retires stage, barrier.
// Race-free at NBUF=2: stage(kt+1) targets buf (kt+1)&1, last read at iter
// kt-1, separated by the end-of-(kt-1) barrier. Tail clamps keep counts exact.
// MODE 0: store f32 gates+bias (x0 projection) to outf (ld 4096)
// MODE 1: LSTM layer-0 epilogue (add = x0proj matrix, incl. both biases)
// MODE 2: LSTM layer-1 epilogue (add = bias per col); also writes feats
// MODE 3: store f32 out + bias (ld 1024), unpermuted (linear head)
template<int MODE>
DEV void gemm_core(int bx, int by,
                   const u16* __restrict__ A0, const u16* __restrict__ A1, int KloA,
                   const u16* __restrict__ Bp, int K,
                   const float* __restrict__ add, float* __restrict__ cst,
                   u16* __restrict__ hout, u16* __restrict__ hout2,
                   float* __restrict__ outf,
                   u16* sA)                          // 2*16384 u16 (64 KB)
{
  const int t = threadIdx.x;                     // 0..511
  const int lane = t & 63;
  const int wm = t >> 6;                         // 0..7
  const int m0 = by*256, n0 = bx*128;

  f32x4 acc[2][8];
#pragma unroll
  for (int i = 0; i < 2; ++i)
#pragma unroll
    for (int j = 0; j < 8; ++j) acc[i][j] = (f32x4){0.f,0.f,0.f,0.f};

  const int kswz = (((t & 7) ^ ((t >> 3) & 7)) << 3);   // pre-swizzled src slot
  const int nkt = K >> 6;

  auto stageA = [&](int kt, int b){
    const int k0 = kt << 6;
    const u16* aPart; int kk;
    if (k0 < KloA){ aPart = A0; kk = k0; } else { aPart = A1; kk = k0 - KloA; }
    u16* dst = sA + b*16384;
#pragma unroll
    for (int p = 0; p < 4; ++p)
      async16(aPart + (size_t)(m0 + p*64 + (t>>3))*1024 + kk + kswz,
              dst + p*4096 + t*8);
  };

  // packed-B wave pointer: 8 j-chunks (8KB) per (bx,kt,ksub)
  const u16* BpL = Bp + lane*8;
  auto loadB = [&](bf16x8* b, int kt, int ksub){
    const u16* p = BpL + ((((size_t)bx*nkt + kt)*2 + ksub) << 12);
#pragma unroll
    for (int j = 0; j < 8; ++j) b[j] = *(const bf16x8*)(p + (size_t)j*512);
  };

  const int rsel = lane >> 4;     // k sub-slot
  const int rxor = lane & 7;      // row&7 for all frag rows (wm*32,i*16 = 0 mod 8)

  bf16x8 bP[8], bQ[8];
  stageA(0, 0);
  loadB(bP, 0, 0);
  asm volatile("s_waitcnt vmcnt(0)" ::: "memory");
  __builtin_amdgcn_sched_barrier(0);
  __builtin_amdgcn_s_barrier();
  __builtin_amdgcn_sched_barrier(0);

  for (int kt = 0; kt < nkt; ++kt){
    const u16* pA = sA + (kt & 1)*16384;
    loadB(bQ, kt, 1);
    { int kts = (kt + 1 < nkt) ? kt + 1 : nkt - 1;        // clamp: exact counts
      stageA(kts, (kt + 1) & 1); }
    // ---- ksub 0: compute with bP ------------------------------------------
    {
      bf16x8 af[2];
#pragma unroll
      for (int i = 0; i < 2; ++i){
        int ra = wm*32 + i*16 + (lane & 15);
        int sl = ((0*4 + rsel) ^ rxor) << 3;
        af[i] = *(const bf16x8*)&pA[ra*64 + sl];
      }
      __builtin_amdgcn_s_setprio(1);
#pragma unroll
      for (int i = 0; i < 2; ++i)
#pragma unroll
        for (int j = 0; j < 8; ++j)
          acc[i][j] = __builtin_amdgcn_mfma_f32_16x16x32_bf16(af[i], bP[j], acc[i][j], 0, 0, 0);
      __builtin_amdgcn_s_setprio(0);
    }
    { int ktn = (kt + 1 < nkt) ? kt + 1 : nkt - 1;
      loadB(bP, ktn, 0); }
    // ---- ksub 1: compute with bQ ------------------------------------------
    {
      bf16x8 af[2];
#pragma unroll
      for (int i = 0; i < 2; ++i){
        int ra = wm*32 + i*16 + (lane & 15);
        int sl = ((1*4 + rsel) ^ rxor) << 3;
        af[i] = *(const bf16x8*)&pA[ra*64 + sl];
      }
      __builtin_amdgcn_s_setprio(1);
#pragma unroll
      for (int i = 0; i < 2; ++i)
#pragma unroll
        for (int j = 0; j < 8; ++j)
          acc[i][j] = __builtin_amdgcn_mfma_f32_16x16x32_bf16(af[i], bQ[j], acc[i][j], 0, 0, 0);
      __builtin_amdgcn_s_setprio(0);
    }
    asm volatile("s_waitcnt vmcnt(8)" ::: "memory");      // A(kt+1) landed (bP' in flight)
    __builtin_amdgcn_sched_barrier(0);
    __builtin_amdgcn_s_barrier();
    __builtin_amdgcn_sched_barrier(0);
  }

  const int s  = lane & 15;
  const int rq = (lane >> 4) * 4;

  if constexpr (MODE == 0 || MODE == 3){
    const int ldc = (MODE == 0) ? 4096 : 1024;
#pragma unroll
    for (int j = 0; j < 8; ++j){
      int col = n0 + j*16 + s;
      float bj = add[col];
#pragma unroll
      for (int i = 0; i < 2; ++i){
        int rowb = m0 + wm*32 + i*16 + rq;
#pragma unroll
        for (int r = 0; r < 4; ++r)
          outf[(size_t)(rowb + r)*ldc + col] = acc[i][j][r] + bj;
      }
    }
  } else {
    // col c = n0 + j*16 + s: gate = j&3, unit u = s + ((bx*2 + (j>>2))<<4)
    float bj[8];
    if constexpr (MODE == 2){
#pragma unroll
      for (int j = 0; j < 8; ++j) bj[j] = add[n0 + j*16 + s];
    }
#pragma unroll
    for (int i = 0; i < 2; ++i){
      int rowb = m0 + wm*32 + i*16 + rq;
#pragma unroll
      for (int r = 0; r < 4; ++r){
        int row = rowb + r;
#pragma unroll
        for (int half = 0; half < 2; ++half){
          float g0, g1, g2, g3;
          if (MODE == 1){
            const float* xp = add + (size_t)row*4096 + n0;
            g0 = acc[i][half*4+0][r] + xp[(half*4+0)*16 + s];
            g1 = acc[i][half*4+1][r] + xp[(half*4+1)*16 + s];
            g2 = acc[i][half*4+2][r] + xp[(half*4+2)*16 + s];
            g3 = acc[i][half*4+3][r] + xp[(half*4+3)*16 + s];
          } else {
            g0 = acc[i][half*4+0][r] + bj[half*4+0];
            g1 = acc[i][half*4+1][r] + bj[half*4+1];
            g2 = acc[i][half*4+2][r] + bj[half*4+2];
            g3 = acc[i][half*4+3][r] + bj[half*4+3];
          }
          float ig = sigf(g0), fg = sigf(g1), gg = tanh_(g2), og = sigf(g3);
          int u = s + ((bx*2 + half) << 4);
          size_t si = (size_t)row*1024 + u;
          float cn = fg * cst[si] + ig * gg;
          cst[si] = cn;
          float hn = og * tanh_(cn);
          u16 hb = f2bf(hn);
          hout[si] = hb;
          if (MODE == 2) hout2[(size_t)row*32768 + u] = hb;  // feats[b][t][u]
        }
      }
    }
  }
}

// ---- standalone GEMM (MODE 0 prep, MODE 3 head). SWZ: bijective XCD chunking
// so the 8 bx-blocks sharing one A-tile land on ONE XCD's L2 (gridDim.x == 8).
template<int MODE, int SWZ>
__global__ __launch_bounds__(512, 2)
void gemm_k(const u16* __restrict__ A0, const u16* __restrict__ Bp, int K,
            const float* __restrict__ add, float* __restrict__ outf)
{
  __shared__ __align__(16) u16 sA[2*16384];
  int bx = blockIdx.x, by = blockIdx.y;
  if constexpr (SWZ){
    int lin = by * (int)gridDim.x + bx;   // hw: XCD = lin & 7
    int xcd = lin & 7, idx = lin >> 3;    // idx within XCD
    int ypt = (int)gridDim.y >> 3;        // by-tiles per XCD
    by = xcd*ypt + (idx >> 3);
    bx = idx & 7;
  }
  gemm_core<MODE>(bx, by, A0, nullptr, 1<<20, Bp, K, add,
                  nullptr, nullptr, nullptr, outf, sA);
}

// ---- fused step: L1(t) (blocks by<4) runs concurrently with L0(t+1) (by>=4).
// roles: 0 = both (grid y=8), 1 = L0 only (y=4), 2 = L1 only (y=4).
__global__ __launch_bounds__(512, 2)
void fused_step(const u16* __restrict__ h0in, const u16* __restrict__ h1in,
                const u16* __restrict__ Whh0p, const u16* __restrict__ W1p,
                const float* __restrict__ X0p, const float* __restrict__ B1,
                float* __restrict__ C0, float* __restrict__ C1,
                u16* __restrict__ h0out, u16* __restrict__ h1out,
                u16* __restrict__ feats, int roles)
{
  __shared__ __align__(16) u16 sA[2*16384];
  int by = blockIdx.y, isL0;
  if (roles == 0){ isL0 = (by >= 4); by &= 3; }
  else isL0 = (roles == 1);
  if (isL0)   // h0(next) = cell(X0p, h0in, C0)
    gemm_core<1>(blockIdx.x, by, h0in, nullptr, 1<<20, Whh0p, 1024, X0p,
                 C0, h0out, nullptr, nullptr, sA);
  else        // h1(next) = cell([h0in|h1in]@W1^T + B1, C1); writes feats
    gemm_core<2>(blockIdx.x, by, h0in, h1in, 1024, W1p, 2048, B1,
                 C1, h1out, feats, nullptr, sA);
}

// ---------------------------------------------------------------------------
extern "C" void kernel_launch(void* const* d_in, const int* in_sizes, int n_in,
                              void* d_out, int out_size, void* d_ws, size_t ws_size,
                              hipStream_t stream)
{
  (void)in_sizes; (void)n_in; (void)out_size; (void)ws_size;
  const float* z    = (const float*)d_in[0];
  const float* gam  = (const float*)d_in[1];
  const float* bet  = (const float*)d_in[2];
  const float* Wih0 = (const float*)d_in[3];
  const float* Whh0 = (const float*)d_in[4];
  const float* bih0 = (const float*)d_in[5];
  const float* bhh0 = (const float*)d_in[6];
  const float* Wih1 = (const float*)d_in[7];
  const float* Whh1 = (const float*)d_in[8];
  const float* bih1 = (const float*)d_in[9];
  const float* bhh1 = (const float*)d_in[10];
  const float* Wlin = (const float*)d_in[11];
  const float* blin = (const float*)d_in[12];
  float* out = (float*)d_out;

  char* p = (char*)d_ws;
  auto alloc = [&](size_t b) -> void* { void* r = (void*)p; p += (b + 255) & ~(size_t)255; return r; };
  u16*  Wih0p = (u16*)alloc((size_t)4096*1024*2);   // packed fragment order
  u16*  Whh0p = (u16*)alloc((size_t)4096*1024*2);
  u16*  W1p   = (u16*)alloc((size_t)4096*2048*2);   // [W_ih1 | W_hh1] along K
  u16*  Wlinp = (u16*)alloc((size_t)1024*1024*2);
  float* Bx0  = (float*)alloc(4096*4);
  float* B1   = (float*)alloc(4096*4);
  float* X0p  = (float*)alloc((size_t)1024*4096*4);
  u16*  H0a   = (u16*)alloc((size_t)1024*1024*2);
  u16*  H0b   = (u16*)alloc((size_t)1024*1024*2);
  u16*  H1a   = (u16*)alloc((size_t)1024*1024*2);
  u16*  H1b   = (u16*)alloc((size_t)1024*1024*2);
  float* C0   = (float*)alloc((size_t)1024*1024*4);
  float* C1   = (float*)alloc((size_t)1024*1024*4);
  u16*  Feats = (u16*)alloc((size_t)1024*32*1024*2);
  float* PS   = (float*)alloc(16*1024*4);
  float* PQ   = (float*)alloc(16*1024*4);
  float* Sc   = (float*)alloc(1024*4);
  float* Sh   = (float*)alloc(1024*4);

  // prep
  bn_stats<<<64, 256, 0, stream>>>(z, PS, PQ);
  bn_fin<<<4, 256, 0, stream>>>(PS, PQ, gam, bet, Sc, Sh);
  bn_norm<<<64, 256, 0, stream>>>(z, Sc, Sh, H0a, H1a, C0, C1);
  // packed weights: chunks = (N/128)*(K/64)*16; grid = chunks/4
  pack_w<<<2048, 256, 0, stream>>>(Wih0, Wih0, 1<<20, 1024, 1, Wih0p);
  pack_w<<<2048, 256, 0, stream>>>(Whh0, Whh0, 1<<20, 1024, 1, Whh0p);
  pack_w<<<4096, 256, 0, stream>>>(Wih1, Whh1, 1024, 2048, 1, W1p);
  pack_w<<< 512, 256, 0, stream>>>(Wlin, Wlin, 1<<20, 1024, 0, Wlinp);
  bias_k<<<16, 256, 0, stream>>>(bih0, bhh0, bih1, bhh1, Bx0, B1);

  // x0_proj = zn @ W_ih0p^T + (b_ih0 + b_hh0)   (constant over steps)
  gemm_k<0,0><<<dim3(32,4), 512, 0, stream>>>(H0a, Wih0p, 1024, Bx0, X0p);

  u16* h0b[2] = {H0a, H0b};
  u16* h1b[2] = {H1a, H1b};

  // h0(1) <- h0(0): L0 alone (nothing to overlap with yet)
  fused_step<<<dim3(32,4), 512, 0, stream>>>(h0b[0], nullptr, Whh0p, W1p, X0p, B1,
                                             C0, C1, h0b[1], nullptr, nullptr, 1);
  // steps t=0..30: L1(t) uses h0(t+1); concurrently L0 computes h0(t+2)
  for (int t = 0; t < 31; ++t){
    fused_step<<<dim3(32,8), 512, 0, stream>>>(
        h0b[(t+1)&1], h1b[t&1], Whh0p, W1p, X0p, B1,
        C0, C1, h0b[t&1], h1b[(t+1)&1], Feats + (size_t)t*1024, 0);
  }
  // final L1(31): uses h0(32)=h0b[0], h1 state h1b[1]
  fused_step<<<dim3(32,4), 512, 0, stream>>>(h0b[0], h1b[1], Whh0p, W1p, X0p, B1,
                                             C0, C1, nullptr, h1b[0], Feats + (size_t)31*1024, 2);

  // out = feats @ W_lin^T + b_lin  (XCD-chunked swizzle for A-tile L2 reuse)
  gemm_k<3,1><<<dim3(8,128), 512, 0, stream>>>(Feats, Wlinp, 1024, blin, out);
}

// Round 7
// 1703.201 us; speedup vs baseline: 1.2506x; 1.2506x over previous
//
#include <hip/hip_runtime.h>

#define DEV __device__ __forceinline__

typedef unsigned short u16;
using bf16x8 = __attribute__((ext_vector_type(8))) __bf16;
using f32x4  = __attribute__((ext_vector_type(4))) float;

DEV u16 f2bf(float f){
  unsigned u = __float_as_uint(f);
  u += 0x7fffu + ((u >> 16) & 1u);   // round-to-nearest-even
  return (u16)(u >> 16);
}
DEV float sigf(float x){ return 1.f / (1.f + __expf(-x)); }
DEV float tanh_(float x){ return 2.f / (1.f + __expf(-2.f*x)) - 1.f; } // safe at +/-inf

// ---------------- packed-A layout (all A regions have K=1024) ----------------
// chunk c = (row>>4)*32 + (u>>5); 1KB chunk: lane l = (row&15) | (((u>>3)&3)<<4)
// holds elems u&7 at [c*512 + l*8 + (u&7)].  Consumed by loadA as one bf16x8
// wave-load per 16-row fragment: af[e] = A[rblk*16 + (l&15)][k32*32 + (l>>4)*8 + e].
DEV void wpack(u16* __restrict__ b, int row, int u, u16 v){
  size_t c = ((size_t)(row >> 4) * 32 + (u >> 5)) << 9;
  b[c + (((row & 15) | (((u >> 3) & 3) << 4)) << 3) + (u & 7)] = v;
}

// ---------------- BatchNorm (training-mode batch stats, biased var) ----------
__global__ void bn_stats(const float* __restrict__ z, float* __restrict__ ps, float* __restrict__ pq){
  int bx = blockIdx.x; int rg = bx >> 2, cg = bx & 3;
  int c = cg*256 + threadIdx.x;
  float s = 0.f, q = 0.f;
  for (int r = rg*64; r < rg*64 + 64; ++r){ float v = z[r*1024 + c]; s += v; q += v*v; }
  ps[rg*1024 + c] = s; pq[rg*1024 + c] = q;
}

__global__ void bn_fin(const float* __restrict__ ps, const float* __restrict__ pq,
                       const float* __restrict__ gam, const float* __restrict__ bet,
                       float* __restrict__ sc, float* __restrict__ sh){
  int c = blockIdx.x*256 + threadIdx.x;
  float s = 0.f, q = 0.f;
  for (int rg = 0; rg < 16; ++rg){ s += ps[rg*1024 + c]; q += pq[rg*1024 + c]; }
  float mean = s * (1.f/1024.f);
  float var  = q * (1.f/1024.f) - mean*mean;
  float k = gam[c] * rsqrtf(var + 1e-5f);
  sc[c] = k; sh[c] = bet[c] - mean*k;
}

// zn -> h0 (packed bf16), h1 (packed bf16), c0 (f32 row-major), c1 (f32)
__global__ void bn_norm(const float* __restrict__ z, const float* __restrict__ sc, const float* __restrict__ sh,
                        u16* __restrict__ h0, u16* __restrict__ h1,
                        float* __restrict__ c0, float* __restrict__ c1){
  int bx = blockIdx.x; int rg = bx >> 2, cg = bx & 3;
  int c = cg*256 + threadIdx.x;
  float k = sc[c], b = sh[c];
  for (int r = rg*64; r < rg*64 + 64; ++r){
    float v = z[r*1024 + c]*k + b;
    u16 hv = f2bf(v);
    wpack(h0, r, c, hv); wpack(h1, r, c, hv);
    c0[r*1024 + c] = v;  c1[r*1024 + c] = v;
  }
}

// ---------------- weight pack: MFMA-fragment order (+gate permutation) -------
// Chunk c = (((bx*nkt + kt)*2 + ksub)*2 + wn)*4 + j: 1KB = 64 lanes x 16B.
// Lane l: B[n = bx*128 + wn*64 + j*16 + (l&15)][k = kt*64+ksub*32+(l>>4)*8 ..+8].
__global__ void pack_w(const float* __restrict__ src0, const float* __restrict__ src1,
                       int KloA, int K, int permute, u16* __restrict__ dst){
  int c = blockIdx.x*4 + (threadIdx.x >> 6);
  int lane = threadIdx.x & 63;
  int j = c & 3, wn = (c>>2)&1, ksub = (c>>3)&1;
  int rest = c >> 4;
  int nkt = K >> 6;
  int kt = rest % nkt, bx = rest / nkt;
  int rn = bx*128 + wn*64 + j*16 + (lane & 15);
  int row = rn;
  if (permute){ int gate=(rn>>4)&3; int u=(rn&15)|((rn>>6)<<4); row=(gate<<10)+u; }
  int k0 = kt*64 + ksub*32 + (lane>>4)*8;
  const float* sp; int kk;
  if (k0 < KloA){ sp = src0; kk = k0; } else { sp = src1; kk = k0 - KloA; }
  const float4* v = (const float4*)(sp + (size_t)row*1024 + kk);
  float4 a = v[0], b = v[1];
  ushort4 o0; o0.x=f2bf(a.x); o0.y=f2bf(a.y); o0.z=f2bf(a.z); o0.w=f2bf(a.w);
  ushort4 o1; o1.x=f2bf(b.x); o1.y=f2bf(b.y); o1.z=f2bf(b.z); o1.w=f2bf(b.w);
  ushort4* d = (ushort4*)(dst + ((size_t)c<<9) + lane*8);
  d[0]=o0; d[1]=o1;
}

__global__ void bias_k(const float* __restrict__ bi0, const float* __restrict__ bh0,
                       const float* __restrict__ bi1, const float* __restrict__ bh1,
                       float* __restrict__ bx0, float* __restrict__ b1){
  int c = blockIdx.x*256 + threadIdx.x;           // 0..4095
  int gate = (c>>4)&3; int u = (c&15) | ((c>>6)<<4); int r = (gate<<10) + u;
  bx0[c] = bi0[r] + bh0[r];
  b1[c]  = bi1[r] + bh1[r];
}

// ---------------- GEMM core: C(128x128) = A(M,K) @ B(N,K)^T, bf16 MFMA ------
// ZERO LDS, ZERO barriers. Both operands fragment-packed in global memory,
// streamed DIRECT global->VGPR as coalesced 1KB wave-loads. Waves fully
// independent; ksub-granular double buffers (aP/aQ, bP/bQ, static names);
// ~12 loads in flight; s_waitcnt inserted by compiler before first use.
// 4 waves 2Mx2N (dup-optimal: A-dup=2, B-dup=2, both L1-absorbed).
// A regions all have K=1024; L1's K=2048 = [h0pack | h1pack] selected per kt.
// MODE 0: store f32 gates+bias (x0 projection) to outf (ld 4096)
// MODE 1: LSTM layer-0 epilogue (add = x0proj matrix, incl. both biases)
// MODE 2: LSTM layer-1 epilogue (add = bias per col); writes packed feats
// MODE 3: store f32 out + bias (ld 1024), unpermuted (linear head)
template<int MODE>
DEV void gemm_core(int bx, int by,
                   const u16* __restrict__ A0, const u16* __restrict__ A1, int KloA,
                   const u16* __restrict__ Bp, int K,
                   const float* __restrict__ add, float* __restrict__ cst,
                   u16* __restrict__ hout, u16* __restrict__ hout2, int tstep,
                   float* __restrict__ outf)
{
  const int t = threadIdx.x;
  const int lane = t & 63;
  const int w = t >> 6, wm = w >> 1, wn = w & 1;
  const int m0 = by*128, n0 = bx*128;

  f32x4 acc[4][4];
#pragma unroll
  for (int i = 0; i < 4; ++i)
#pragma unroll
    for (int j = 0; j < 4; ++j) acc[i][j] = (f32x4){0.f,0.f,0.f,0.f};

  const int nkt = K >> 6;
  const int rblk0 = (m0 >> 4) + wm*4;           // wave's first 16-row block

  // packed-A: chunk rblk*32 + k32; frag i stride = 32 chunks = 16384 u16
  auto loadA = [&](bf16x8* a, int kt, int ksub){
    const int k0 = kt << 6;
    const u16* base; int ktl;
    if (k0 < KloA){ base = A0; ktl = kt; } else { base = A1; ktl = kt - (KloA >> 6); }
    const u16* p = base + (((size_t)rblk0*32 + ktl*2 + ksub) << 9) + lane*8;
#pragma unroll
    for (int i = 0; i < 4; ++i) a[i] = *(const bf16x8*)(p + (size_t)i*16384);
  };

  // packed-B wave pointer: 4 j-chunks contiguous (4KB) per (kt,ksub,wn)
  const u16* BpL = Bp + lane*8;
  auto loadB = [&](bf16x8* b, int kt, int ksub){
    const u16* p = BpL + (((((size_t)bx*nkt + kt)*2 + ksub)*2 + wn) << 11);
#pragma unroll
    for (int j = 0; j < 4; ++j) b[j] = *(const bf16x8*)(p + (size_t)j*512);
  };

  bf16x8 aP[4], aQ[4], bP[4], bQ[4];
  loadA(aP, 0, 0); loadB(bP, 0, 0);

  for (int kt = 0; kt < nkt; ++kt){
    // ---- ksub 0: compute aP x bP; prefetch ksub1 --------------------------
    loadA(aQ, kt, 1); loadB(bQ, kt, 1);
    __builtin_amdgcn_s_setprio(1);
#pragma unroll
    for (int i = 0; i < 4; ++i)
#pragma unroll
      for (int j = 0; j < 4; ++j)
        acc[i][j] = __builtin_amdgcn_mfma_f32_16x16x32_bf16(aP[i], bP[j], acc[i][j], 0, 0, 0);
    __builtin_amdgcn_s_setprio(0);
    // ---- ksub 1: compute aQ x bQ; prefetch next kt ------------------------
    { int ktn = (kt + 1 < nkt) ? kt + 1 : nkt - 1;
      loadA(aP, ktn, 0); loadB(bP, ktn, 0); }
    __builtin_amdgcn_s_setprio(1);
#pragma unroll
    for (int i = 0; i < 4; ++i)
#pragma unroll
      for (int j = 0; j < 4; ++j)
        acc[i][j] = __builtin_amdgcn_mfma_f32_16x16x32_bf16(aQ[i], bQ[j], acc[i][j], 0, 0, 0);
    __builtin_amdgcn_s_setprio(0);
  }

  const int s  = lane & 15;
  const int rq = (lane >> 4) * 4;

  if constexpr (MODE == 0 || MODE == 3){
    const int ldc = (MODE == 0) ? 4096 : 1024;
#pragma unroll
    for (int j = 0; j < 4; ++j){
      int col = n0 + wn*64 + j*16 + s;
      float bj = add[col];
#pragma unroll
      for (int i = 0; i < 4; ++i){
        int rowb = m0 + wm*64 + i*16 + rq;
#pragma unroll
        for (int r = 0; r < 4; ++r)
          outf[(size_t)(rowb + r)*ldc + col] = acc[i][j][r] + bj;
      }
    }
  } else {
    const int u = s + ((bx*2 + wn) << 4);     // hidden-unit index 0..1023
    int cidx[4]; float bj[4];
#pragma unroll
    for (int j = 0; j < 4; ++j){
      cidx[j] = n0 + wn*64 + j*16 + s;        // gate j lives at this col
      if (MODE == 2) bj[j] = add[cidx[j]];
    }
#pragma unroll
    for (int i = 0; i < 4; ++i){
      int rowb = m0 + wm*64 + i*16 + rq;
#pragma unroll
      for (int r = 0; r < 4; ++r){
        int row = rowb + r;
        float g0, g1, g2, g3;
        if (MODE == 1){
          const float* xp = add + (size_t)row*4096;
          g0 = acc[i][0][r] + xp[cidx[0]];
          g1 = acc[i][1][r] + xp[cidx[1]];
          g2 = acc[i][2][r] + xp[cidx[2]];
          g3 = acc[i][3][r] + xp[cidx[3]];
        } else {
          g0 = acc[i][0][r] + bj[0];
          g1 = acc[i][1][r] + bj[1];
          g2 = acc[i][2][r] + bj[2];
          g3 = acc[i][3][r] + bj[3];
        }
        float ig = sigf(g0), fg = sigf(g1), gg = tanh_(g2), og = sigf(g3);
        size_t si = (size_t)row*1024 + u;
        float cn = fg * cst[si] + ig * gg;
        cst[si] = cn;
        float hn = og * tanh_(cn);
        u16 hb = f2bf(hn);
        wpack(hout, row, u, hb);              // packed-A layout for next GEMM
        if (MODE == 2){
          // Feats packed: head-A row r = row*32 + tstep
          size_t cch = ((size_t)(row*2 + (tstep >> 4))*32 + (u >> 5)) << 9;
          hout2[cch + (((tstep & 15) | (((u >> 3) & 3) << 4)) << 3) + (u & 7)] = hb;
        }
      }
    }
  }
}

// ---- standalone GEMM (MODE 0 prep, MODE 3 head). SWZ: bijective XCD chunking
// so the 8 bx-blocks sharing one A-tile land on ONE XCD's L2 (grid (8,256)).
template<int MODE, int SWZ>
__global__ __launch_bounds__(256)
void gemm_k(const u16* __restrict__ A0, const u16* __restrict__ Bp, int K,
            const float* __restrict__ add, float* __restrict__ outf)
{
  int bx = blockIdx.x, by = blockIdx.y;
  if constexpr (SWZ){
    int lin = by * (int)gridDim.x + bx;   // hw: XCD = lin & 7
    int xcd = lin & 7, idx = lin >> 3;    // idx 0..255 within XCD
    by = xcd*32 + (idx >> 3);             // each XCD: 32 contiguous by-tiles
    bx = idx & 7;
  }
  gemm_core<MODE>(bx, by, A0, nullptr, 1<<20, Bp, K, add,
                  nullptr, nullptr, nullptr, 0, outf);
}

// ---- fused step: roles 0 = both (grid (32,16), linear-ID parity interleaves
// L0/L1 so adjacent dispatch IDs mix roles -> CU-level balance);
// 1 = L0 only (grid (32,8)); 2 = L1 only (grid (32,8)).
__global__ __launch_bounds__(256)
void fused_step(const u16* __restrict__ h0in, const u16* __restrict__ h1in,
                const u16* __restrict__ Whh0p, const u16* __restrict__ W1p,
                const float* __restrict__ X0p, const float* __restrict__ B1,
                float* __restrict__ C0, float* __restrict__ C1,
                u16* __restrict__ h0out, u16* __restrict__ h1out,
                u16* __restrict__ feats, int tstep, int roles)
{
  int bx, by, isL0;
  if (roles == 0){
    int lin = blockIdx.y * (int)gridDim.x + blockIdx.x;   // 0..511
    isL0 = lin & 1;
    int tile = lin >> 1;                                  // 0..255
    by = tile >> 5; bx = tile & 31;
  } else {
    isL0 = (roles == 1); by = blockIdx.y; bx = blockIdx.x;
  }
  if (isL0)   // h0(next) = cell(X0p, h0in, C0)
    gemm_core<1>(bx, by, h0in, nullptr, 1<<20, Whh0p, 1024, X0p,
                 C0, h0out, nullptr, 0, nullptr);
  else        // h1(next) = cell([h0in|h1in]@W1^T + B1, C1); writes packed feats
    gemm_core<2>(bx, by, h0in, h1in, 1024, W1p, 2048, B1,
                 C1, h1out, feats, tstep, nullptr);
}

// ---------------------------------------------------------------------------
extern "C" void kernel_launch(void* const* d_in, const int* in_sizes, int n_in,
                              void* d_out, int out_size, void* d_ws, size_t ws_size,
                              hipStream_t stream)
{
  (void)in_sizes; (void)n_in; (void)out_size; (void)ws_size;
  const float* z    = (const float*)d_in[0];
  const float* gam  = (const float*)d_in[1];
  const float* bet  = (const float*)d_in[2];
  const float* Wih0 = (const float*)d_in[3];
  const float* Whh0 = (const float*)d_in[4];
  const float* bih0 = (const float*)d_in[5];
  const float* bhh0 = (const float*)d_in[6];
  const float* Wih1 = (const float*)d_in[7];
  const float* Whh1 = (const float*)d_in[8];
  const float* bih1 = (const float*)d_in[9];
  const float* bhh1 = (const float*)d_in[10];
  const float* Wlin = (const float*)d_in[11];
  const float* blin = (const float*)d_in[12];
  float* out = (float*)d_out;

  char* p = (char*)d_ws;
  auto alloc = [&](size_t b) -> void* { void* r = (void*)p; p += (b + 255) & ~(size_t)255; return r; };
  u16*  Wih0p = (u16*)alloc((size_t)4096*1024*2);   // packed fragment order
  u16*  Whh0p = (u16*)alloc((size_t)4096*1024*2);
  u16*  W1p   = (u16*)alloc((size_t)4096*2048*2);   // [W_ih1 | W_hh1] along K
  u16*  Wlinp = (u16*)alloc((size_t)1024*1024*2);
  float* Bx0  = (float*)alloc(4096*4);
  float* B1   = (float*)alloc(4096*4);
  float* X0p  = (float*)alloc((size_t)1024*4096*4);
  u16*  H0a   = (u16*)alloc((size_t)1024*1024*2);   // packed-A regions
  u16*  H0b   = (u16*)alloc((size_t)1024*1024*2);
  u16*  H1a   = (u16*)alloc((size_t)1024*1024*2);
  u16*  H1b   = (u16*)alloc((size_t)1024*1024*2);
  float* C0   = (float*)alloc((size_t)1024*1024*4);
  float* C1   = (float*)alloc((size_t)1024*1024*4);
  u16*  Feats = (u16*)alloc((size_t)1024*32*1024*2); // packed (head-A layout)
  float* PS   = (float*)alloc(16*1024*4);
  float* PQ   = (float*)alloc(16*1024*4);
  float* Sc   = (float*)alloc(1024*4);
  float* Sh   = (float*)alloc(1024*4);

  // prep
  bn_stats<<<64, 256, 0, stream>>>(z, PS, PQ);
  bn_fin<<<4, 256, 0, stream>>>(PS, PQ, gam, bet, Sc, Sh);
  bn_norm<<<64, 256, 0, stream>>>(z, Sc, Sh, H0a, H1a, C0, C1);
  // packed weights: chunks = (N/128)*(K/64)*16; grid = chunks/4
  pack_w<<<2048, 256, 0, stream>>>(Wih0, Wih0, 1<<20, 1024, 1, Wih0p);
  pack_w<<<2048, 256, 0, stream>>>(Whh0, Whh0, 1<<20, 1024, 1, Whh0p);
  pack_w<<<4096, 256, 0, stream>>>(Wih1, Whh1, 1024, 2048, 1, W1p);
  pack_w<<< 512, 256, 0, stream>>>(Wlin, Wlin, 1<<20, 1024, 0, Wlinp);
  bias_k<<<16, 256, 0, stream>>>(bih0, bhh0, bih1, bhh1, Bx0, B1);

  // x0_proj = zn @ W_ih0p^T + (b_ih0 + b_hh0)   (constant over steps)
  gemm_k<0,0><<<dim3(32,8), 256, 0, stream>>>(H0a, Wih0p, 1024, Bx0, X0p);

  u16* h0b[2] = {H0a, H0b};
  u16* h1b[2] = {H1a, H1b};

  // h0(1) <- h0(0): L0 alone (nothing to overlap with yet)
  fused_step<<<dim3(32,8), 256, 0, stream>>>(h0b[0], nullptr, Whh0p, W1p, X0p, B1,
                                             C0, C1, h0b[1], nullptr, nullptr, 0, 1);
  // steps t=0..30: L1(t) uses h0(t+1); concurrently L0 computes h0(t+2)
  for (int t = 0; t < 31; ++t){
    fused_step<<<dim3(32,16), 256, 0, stream>>>(
        h0b[(t+1)&1], h1b[t&1], Whh0p, W1p, X0p, B1,
        C0, C1, h0b[t&1], h1b[(t+1)&1], Feats, t, 0);
  }
  // final L1(31): uses h0(32)=h0b[0], h1 state h1b[1]
  fused_step<<<dim3(32,8), 256, 0, stream>>>(h0b[0], h1b[1], Whh0p, W1p, X0p, B1,
                                             C0, C1, nullptr, h1b[0], Feats, 31, 2);

  // out = feats @ W_lin^T + b_lin  (XCD-chunked swizzle for A-tile L2 reuse)
  gemm_k<3,1><<<dim3(8,256), 256, 0, stream>>>(Feats, Wlinp, 1024, blin, out);
}